// Round 2
// baseline (285.132 us; speedup 1.0000x reference)
//
#include <hip/hip_runtime.h>

// ---- zero small stats buffer (ws is poisoned 0xAA each call) ----
__global__ void k_zero(float* __restrict__ p, int n){
  int i = blockIdx.x * blockDim.x + threadIdx.x;
  if (i < n) p[i] = 0.f;
}

// ---- depthwise 3x3, pad 1: tmp_dw[b,c,y,x] = sum_{3x3} in * w_dw[c] ----
__global__ void k_dw(const float* __restrict__ in, const float* __restrict__ w,
                     float* __restrict__ out){
  int idx = blockIdx.x * 256 + threadIdx.x;          // b*2^20 + c*2^14 + y*128 + x
  int x = idx & 127, y = (idx >> 7) & 127, c = (idx >> 14) & 63;
  int b = idx >> 20;
  const float* p = in + (((long)(b * 64 + c)) << 14);
  float wv[9];
  #pragma unroll
  for (int i = 0; i < 9; i++) wv[i] = w[c * 9 + i];
  float acc = 0.f;
  #pragma unroll
  for (int dy = 0; dy < 3; dy++){
    int yy = y + dy - 1;
    if ((unsigned)yy < 128u){
      #pragma unroll
      for (int dx = 0; dx < 3; dx++){
        int xx = x + dx - 1;
        if ((unsigned)xx < 128u) acc += p[(yy << 7) + xx] * wv[dy * 3 + dx];
      }
    }
  }
  out[idx] = acc;
}

// ---- pointwise 1x1: h[b,o,y,x] = sum_c tmp_dw[b,c,y,x] * w_pw[o,c] ----
__global__ void k_pw(const float* __restrict__ dw, const float* __restrict__ wpw,
                     float* __restrict__ h){
  int idx = blockIdx.x * 256 + threadIdx.x;
  int sp = idx & 16383;
  int o = (idx >> 14) & 63;
  int b = idx >> 20;
  const float* p = dw + ((long)b << 20) + sp;
  const float* wr = wpw + o * 64;                    // o uniform per block -> scalar loads
  float acc = 0.f;
  #pragma unroll 8
  for (int c = 0; c < 64; c++) acc += p[(long)c << 14] * wr[c];
  h[idx] = acc;
}

// ---- reduce 1x1 (64->16) from ORIGINAL input + BN stats accumulation ----
__global__ void k_red(const float* __restrict__ in, const float* __restrict__ wred,
                      float* __restrict__ r, float* __restrict__ stats){
  int idx = blockIdx.x * 256 + threadIdx.x;          // b*2^18 + c*2^14 + sp
  int sp = idx & 16383;
  int c = (idx >> 14) & 15;                          // uniform per block (2^14 % 256 == 0)
  int b = idx >> 18;
  const float* p = in + ((long)b << 20) + sp;
  const float* wr = wred + c * 64;
  float acc = 0.f;
  #pragma unroll 8
  for (int o = 0; o < 64; o++) acc += p[(long)o << 14] * wr[o];
  r[idx] = acc;

  __shared__ float s1[256], s2[256];
  int t = threadIdx.x;
  s1[t] = acc; s2[t] = acc * acc;
  __syncthreads();
  #pragma unroll
  for (int s = 128; s > 0; s >>= 1){
    if (t < s){ s1[t] += s1[t + s]; s2[t] += s2[t + s]; }
    __syncthreads();
  }
  if (t == 0){
    atomicAdd(&stats[2 * c],     s1[0]);
    atomicAdd(&stats[2 * c + 1], s2[0]);
  }
}

// ---- BN finalize: scale/bias per channel (training-mode, biased var) ----
__global__ void k_bn(const float* __restrict__ stats, const float* __restrict__ gamma,
                     const float* __restrict__ beta, float* __restrict__ sb){
  int c = threadIdx.x;
  if (c < 16){
    const float n = 65536.f;                         // B*H*W
    float mean = stats[2 * c] / n;
    float var  = stats[2 * c + 1] / n - mean * mean;
    float inv  = rsqrtf(var + 1e-5f);
    float sc   = gamma[c] * inv;
    sb[2 * c]     = sc;
    sb[2 * c + 1] = beta[c] - mean * sc;
  }
}

// ---- main involution: per (b, g, 16x16 tile) ----
// out[b, g*4+cg, y, x] = sum_k kern[k] * h[b, g*4+cg, y+kh-3, x+kw-3]
// kern[k] = sum_c relu(bn(r[b,c,y,x])) * w_span[g*49+k, c]
__launch_bounds__(256)
__global__ void k_main(const float* __restrict__ h, const float* __restrict__ r,
                       const float* __restrict__ sb, const float* __restrict__ wspan,
                       float* __restrict__ out){
  __shared__ float s_h[4][22][23];                   // +1 pad col: worst 2-way bank alias (free)
  __shared__ float s_span[784];                      // 49 x 16
  int t = threadIdx.x;
  int g = blockIdx.y, b = blockIdx.z;
  int tx0 = (blockIdx.x & 7) << 4, ty0 = (blockIdx.x >> 3) << 4;

  for (int i = t; i < 784; i += 256) s_span[i] = wspan[g * 784 + i];

  const float* hp = h + (((long)(b * 64 + g * 4)) << 14);
  for (int i = t; i < 1936; i += 256){               // 4 ch x 22 x 22 halo tile
    int cg = i / 484, rem = i - cg * 484;
    int ry = rem / 22, rx = rem - ry * 22;
    int yy = ty0 + ry - 3, xx = tx0 + rx - 3;
    float v = 0.f;
    if ((unsigned)yy < 128u && (unsigned)xx < 128u)
      v = hp[((long)cg << 14) + (yy << 7) + xx];
    s_h[cg][ry][rx] = v;
  }

  int ltx = t & 15, lty = t >> 4;
  int px = tx0 + ltx, py = ty0 + lty;
  const float* rp = r + ((long)b << 18) + (py << 7) + px;
  float rv[16];
  #pragma unroll
  for (int c = 0; c < 16; c++){
    float v = rp[(long)c << 14];
    rv[c] = fmaxf(v * sb[2 * c] + sb[2 * c + 1], 0.f);
  }
  __syncthreads();

  float kern[49];
  #pragma unroll
  for (int k = 0; k < 49; k++){
    float a = 0.f;
    #pragma unroll
    for (int c = 0; c < 16; c++) a += rv[c] * s_span[k * 16 + c];
    kern[k] = a;
  }

  long obase = (((long)(b * 64 + g * 4)) << 14) + (py << 7) + px;
  #pragma unroll
  for (int cg = 0; cg < 4; cg++){
    float acc = 0.f;
    #pragma unroll
    for (int kh = 0; kh < 7; kh++)
      #pragma unroll
      for (int kw = 0; kw < 7; kw++)
        acc += kern[kh * 7 + kw] * s_h[cg][lty + kh][ltx + kw];
    out[obase + ((long)cg << 14)] = acc;
  }
}

extern "C" void kernel_launch(void* const* d_in, const int* in_sizes, int n_in,
                              void* d_out, int out_size, void* d_ws, size_t ws_size,
                              hipStream_t stream){
  const float* in       = (const float*)d_in[0];
  const float* w_dw     = (const float*)d_in[1];
  const float* w_pw     = (const float*)d_in[2];
  const float* gamma    = (const float*)d_in[3];
  const float* beta     = (const float*)d_in[4];
  const float* w_reduce = (const float*)d_in[5];
  const float* w_span   = (const float*)d_in[6];
  float* out = (float*)d_out;

  float* ws     = (float*)d_ws;
  float* tmp_dw = ws;                  // 4194304 floats
  float* h      = ws + 4194304;        // 4194304 floats
  float* r      = ws + 8388608;        // 1048576 floats
  float* stats  = ws + 9437184;        // 32 floats (sum, sumsq per channel)
  float* sb     = ws + 9437216;        // 32 floats (scale, bias per channel)

  k_zero<<<1, 64, 0, stream>>>(stats, 32);
  k_dw  <<<16384, 256, 0, stream>>>(in, w_dw, tmp_dw);
  k_pw  <<<16384, 256, 0, stream>>>(tmp_dw, w_pw, h);
  k_red <<<4096, 256, 0, stream>>>(in, w_reduce, r, stats);
  k_bn  <<<1, 16, 0, stream>>>(stats, gamma, beta, sb);
  dim3 grid(64, 16, 4);
  k_main<<<grid, 256, 0, stream>>>(h, r, sb, w_span, out);
}

// Round 3
// 228.192 us; speedup vs baseline: 1.2495x; 1.2495x over previous
//
#include <hip/hip_runtime.h>

// ---- zero small stats buffer (ws is poisoned 0xAA each call) ----
__global__ void k_zero(float* __restrict__ p, int n){
  int i = blockIdx.x * blockDim.x + threadIdx.x;
  if (i < n) p[i] = 0.f;
}

// ---- depthwise 3x3, pad 1: tmp_dw[b,c,y,x] = sum_{3x3} in * w_dw[c] ----
__global__ void k_dw(const float* __restrict__ in, const float* __restrict__ w,
                     float* __restrict__ out){
  int idx = blockIdx.x * 256 + threadIdx.x;          // b*2^20 + c*2^14 + y*128 + x
  int x = idx & 127, y = (idx >> 7) & 127, c = (idx >> 14) & 63;
  int b = idx >> 20;
  const float* p = in + (((long)(b * 64 + c)) << 14);
  float wv[9];
  #pragma unroll
  for (int i = 0; i < 9; i++) wv[i] = w[c * 9 + i];
  float acc = 0.f;
  #pragma unroll
  for (int dy = 0; dy < 3; dy++){
    int yy = y + dy - 1;
    if ((unsigned)yy < 128u){
      #pragma unroll
      for (int dx = 0; dx < 3; dx++){
        int xx = x + dx - 1;
        if ((unsigned)xx < 128u) acc += p[(yy << 7) + xx] * wv[dy * 3 + dx];
      }
    }
  }
  out[idx] = acc;
}

// ---- pointwise 1x1: one thread per sp, all 64 outputs in registers ----
// h[b,o,sp] = sum_c tmp_dw[b,c,sp] * w_pw[o,c]
__launch_bounds__(256)
__global__ void k_pw(const float* __restrict__ dw, const float* __restrict__ wpw,
                     float* __restrict__ h){
  int tid = blockIdx.x * 256 + threadIdx.x;          // b*16384 + sp
  int sp = tid & 16383;
  int b  = tid >> 14;
  const float* p = dw + ((long)b << 20) + sp;
  float acc[64];
  #pragma unroll
  for (int o = 0; o < 64; o++) acc[o] = 0.f;
  #pragma unroll 4
  for (int c = 0; c < 64; c++){
    float v = p[(long)c << 14];                      // coalesced across lanes
    #pragma unroll
    for (int o = 0; o < 64; o++) acc[o] += v * wpw[o * 64 + c];  // uniform -> s_load
  }
  float* hp = h + ((long)b << 20) + sp;
  #pragma unroll
  for (int o = 0; o < 64; o++) hp[(long)o << 14] = acc[o];
}

// ---- reduce 1x1 (64->16): one thread per sp, all 16 outputs + BN stats ----
__launch_bounds__(256)
__global__ void k_red(const float* __restrict__ in, const float* __restrict__ wred,
                      float* __restrict__ r, float* __restrict__ stats){
  int tid = blockIdx.x * 256 + threadIdx.x;          // b*16384 + sp
  int sp = tid & 16383;
  int b  = tid >> 14;
  const float* p = in + ((long)b << 20) + sp;
  float racc[16];
  #pragma unroll
  for (int c = 0; c < 16; c++) racc[c] = 0.f;
  #pragma unroll 8
  for (int o = 0; o < 64; o++){
    float v = p[(long)o << 14];
    #pragma unroll
    for (int c = 0; c < 16; c++) racc[c] += v * wred[c * 64 + o];  // uniform -> s_load
  }
  float* rp = r + ((long)b << 18) + sp;
  #pragma unroll
  for (int c = 0; c < 16; c++) rp[(long)c << 14] = racc[c];

  // BN stats: wave shuffle-reduce, then cross-wave via LDS, then 32 atomics/block
  int lane = threadIdx.x & 63, wv = threadIdx.x >> 6;
  __shared__ float sw[4][32];
  #pragma unroll
  for (int c = 0; c < 16; c++){
    float v = racc[c], q = racc[c] * racc[c];
    #pragma unroll
    for (int off = 32; off > 0; off >>= 1){
      v += __shfl_down(v, off, 64);
      q += __shfl_down(q, off, 64);
    }
    if (lane == 0){ sw[wv][2 * c] = v; sw[wv][2 * c + 1] = q; }
  }
  __syncthreads();
  if (threadIdx.x < 32){
    float a = sw[0][threadIdx.x] + sw[1][threadIdx.x]
            + sw[2][threadIdx.x] + sw[3][threadIdx.x];
    atomicAdd(&stats[threadIdx.x], a);
  }
}

// ---- BN finalize: scale/bias per channel (training-mode, biased var) ----
__global__ void k_bn(const float* __restrict__ stats, const float* __restrict__ gamma,
                     const float* __restrict__ beta, float* __restrict__ sb){
  int c = threadIdx.x;
  if (c < 16){
    const float n = 65536.f;                         // B*H*W
    float mean = stats[2 * c] / n;
    float var  = stats[2 * c + 1] / n - mean * mean;
    float inv  = rsqrtf(var + 1e-5f);
    float sc   = gamma[c] * inv;
    sb[2 * c]     = sc;
    sb[2 * c + 1] = beta[c] - mean * sc;
  }
}

// ---- main involution: per (b, g, 16x16 tile) ----
// out[b, g*4+cg, y, x] = sum_k kern[k] * h[b, g*4+cg, y+kh-3, x+kw-3]
// kern[k] = sum_c relu(bn(r[b,c,y,x])) * w_span[g*49+k, c]
__launch_bounds__(256)
__global__ void k_main(const float* __restrict__ h, const float* __restrict__ r,
                       const float* __restrict__ sb, const float* __restrict__ wspan,
                       float* __restrict__ out){
  __shared__ float s_h[4][22][23];                   // +1 pad col: worst 2-way bank alias (free)
  int t = threadIdx.x;
  int g = blockIdx.y, b = blockIdx.z;
  int tx0 = (blockIdx.x & 7) << 4, ty0 = (blockIdx.x >> 3) << 4;

  const float* hp = h + (((long)(b * 64 + g * 4)) << 14);
  for (int i = t; i < 1936; i += 256){               // 4 ch x 22 x 22 halo tile
    int cg = i / 484, rem = i - cg * 484;
    int ry = rem / 22, rx = rem - ry * 22;
    int yy = ty0 + ry - 3, xx = tx0 + rx - 3;
    float v = 0.f;
    if ((unsigned)yy < 128u && (unsigned)xx < 128u)
      v = hp[((long)cg << 14) + (yy << 7) + xx];
    s_h[cg][ry][rx] = v;
  }

  int ltx = t & 15, lty = t >> 4;
  int px = tx0 + ltx, py = ty0 + lty;
  const float* rp = r + ((long)b << 18) + (py << 7) + px;
  float rv[16];
  #pragma unroll
  for (int c = 0; c < 16; c++){
    float v = rp[(long)c << 14];
    rv[c] = fmaxf(v * sb[2 * c] + sb[2 * c + 1], 0.f);  // sb uniform -> s_load
  }
  __syncthreads();

  // kernel generation: w_span addresses are wave-uniform -> scalar-pipe s_loads
  const float* wsp = wspan + g * 784;
  float kern[49];
  #pragma unroll
  for (int k = 0; k < 49; k++){
    float a = 0.f;
    #pragma unroll
    for (int c = 0; c < 16; c++) a += rv[c] * wsp[k * 16 + c];
    kern[k] = a;
  }

  long obase = (((long)(b * 64 + g * 4)) << 14) + (py << 7) + px;
  #pragma unroll
  for (int cg = 0; cg < 4; cg++){
    float acc = 0.f;
    #pragma unroll
    for (int kh = 0; kh < 7; kh++)
      #pragma unroll
      for (int kw = 0; kw < 7; kw++)
        acc += kern[kh * 7 + kw] * s_h[cg][lty + kh][ltx + kw];
    out[obase + ((long)cg << 14)] = acc;
  }
}

extern "C" void kernel_launch(void* const* d_in, const int* in_sizes, int n_in,
                              void* d_out, int out_size, void* d_ws, size_t ws_size,
                              hipStream_t stream){
  const float* in       = (const float*)d_in[0];
  const float* w_dw     = (const float*)d_in[1];
  const float* w_pw     = (const float*)d_in[2];
  const float* gamma    = (const float*)d_in[3];
  const float* beta     = (const float*)d_in[4];
  const float* w_reduce = (const float*)d_in[5];
  const float* w_span   = (const float*)d_in[6];
  float* out = (float*)d_out;

  float* ws     = (float*)d_ws;
  float* tmp_dw = ws;                  // 4194304 floats
  float* h      = ws + 4194304;        // 4194304 floats
  float* r      = ws + 8388608;        // 1048576 floats
  float* stats  = ws + 9437184;        // 32 floats (sum, sumsq per channel)
  float* sb     = ws + 9437216;        // 32 floats (scale, bias per channel)

  k_zero<<<1, 64, 0, stream>>>(stats, 32);
  k_dw  <<<16384, 256, 0, stream>>>(in, w_dw, tmp_dw);
  k_pw  <<<256, 256, 0, stream>>>(tmp_dw, w_pw, h);
  k_red <<<256, 256, 0, stream>>>(in, w_reduce, r, stats);
  k_bn  <<<1, 16, 0, stream>>>(stats, gamma, beta, sb);
  dim3 grid(64, 16, 4);
  k_main<<<grid, 256, 0, stream>>>(h, r, sb, w_span, out);
}

// Round 4
// 181.576 us; speedup vs baseline: 1.5703x; 1.2567x over previous
//
#include <hip/hip_runtime.h>

// ---- zero small stats buffer (ws is poisoned 0xAA each call) ----
__global__ void k_zero(float* __restrict__ p, int n){
  int i = blockIdx.x * blockDim.x + threadIdx.x;
  if (i < n) p[i] = 0.f;
}

// ---- depthwise 3x3, pad 1: tmp_dw[b,c,y,x] = sum_{3x3} in * w_dw[c] ----
__global__ void k_dw(const float* __restrict__ in, const float* __restrict__ w,
                     float* __restrict__ out){
  int idx = blockIdx.x * 256 + threadIdx.x;          // b*2^20 + c*2^14 + y*128 + x
  int x = idx & 127, y = (idx >> 7) & 127, c = (idx >> 14) & 63;
  int b = idx >> 20;
  const float* p = in + (((long)(b * 64 + c)) << 14);
  float wv[9];
  #pragma unroll
  for (int i = 0; i < 9; i++) wv[i] = w[c * 9 + i];
  float acc = 0.f;
  #pragma unroll
  for (int dy = 0; dy < 3; dy++){
    int yy = y + dy - 1;
    if ((unsigned)yy < 128u){
      #pragma unroll
      for (int dx = 0; dx < 3; dx++){
        int xx = x + dx - 1;
        if ((unsigned)xx < 128u) acc += p[(yy << 7) + xx] * wv[dy * 3 + dx];
      }
    }
  }
  out[idx] = acc;
}

// ---- pointwise 1x1: thread computes 16 of 64 outputs (q-chunk per block) ----
// h[b,o,sp] = sum_c tmp_dw[b,c,sp] * w_pw[o,c]
__launch_bounds__(256)
__global__ void k_pw(const float* __restrict__ dw, const float* __restrict__ wpw,
                     float* __restrict__ h){
  int blk = blockIdx.x;                              // b*256 + q*64 + sp_blk
  int sp = ((blk & 63) << 8) + threadIdx.x;
  int q  = (blk >> 6) & 3;                           // outputs 16q .. 16q+15
  int b  = blk >> 8;
  const float* p  = dw + ((long)b << 20) + sp;
  const float* wq = wpw + (q << 4) * 64;             // uniform per block -> s_load
  float acc[16];
  #pragma unroll
  for (int j = 0; j < 16; j++) acc[j] = 0.f;
  #pragma unroll 8
  for (int c = 0; c < 64; c++){
    float v = p[(long)c << 14];                      // coalesced across lanes
    #pragma unroll
    for (int j = 0; j < 16; j++) acc[j] += v * wq[j * 64 + c];
  }
  float* hp = h + ((long)b << 20) + ((long)q << 18) + sp;
  #pragma unroll
  for (int j = 0; j < 16; j++) hp[(long)j << 14] = acc[j];
}

// ---- reduce 1x1 (64->16): thread computes 4 of 16 outputs + BN stats ----
__launch_bounds__(256)
__global__ void k_red(const float* __restrict__ in, const float* __restrict__ wred,
                      float* __restrict__ r, float* __restrict__ stats){
  int blk = blockIdx.x;                              // b*256 + q*64 + sp_blk
  int sp = ((blk & 63) << 8) + threadIdx.x;
  int q  = (blk >> 6) & 3;                           // channels 4q .. 4q+3
  int b  = blk >> 8;
  const float* p  = in + ((long)b << 20) + sp;
  const float* wq = wred + (q << 2) * 64;            // uniform -> s_load
  float racc[4] = {0.f, 0.f, 0.f, 0.f};
  #pragma unroll 8
  for (int o = 0; o < 64; o++){
    float v = p[(long)o << 14];
    #pragma unroll
    for (int j = 0; j < 4; j++) racc[j] += v * wq[j * 64 + o];
  }
  float* rp = r + ((long)b << 18) + ((long)q << 16) + sp;
  #pragma unroll
  for (int j = 0; j < 4; j++) rp[(long)j << 14] = racc[j];

  // BN stats: wave shuffle-reduce (8 values), cross-wave via LDS, 8 atomics/block
  int lane = threadIdx.x & 63, wv = threadIdx.x >> 6;
  __shared__ float sw[4][8];
  #pragma unroll
  for (int j = 0; j < 4; j++){
    float v = racc[j], s2 = racc[j] * racc[j];
    #pragma unroll
    for (int off = 32; off > 0; off >>= 1){
      v  += __shfl_down(v,  off, 64);
      s2 += __shfl_down(s2, off, 64);
    }
    if (lane == 0){ sw[wv][2 * j] = v; sw[wv][2 * j + 1] = s2; }
  }
  __syncthreads();
  if (threadIdx.x < 8){
    float a = sw[0][threadIdx.x] + sw[1][threadIdx.x]
            + sw[2][threadIdx.x] + sw[3][threadIdx.x];
    atomicAdd(&stats[(q << 3) + threadIdx.x], a);    // stats[2c+s], c=4q+j
  }
}

// ---- BN finalize: scale/bias per channel (training-mode, biased var) ----
__global__ void k_bn(const float* __restrict__ stats, const float* __restrict__ gamma,
                     const float* __restrict__ beta, float* __restrict__ sb){
  int c = threadIdx.x;
  if (c < 16){
    const float n = 65536.f;                         // B*H*W
    float mean = stats[2 * c] / n;
    float var  = stats[2 * c + 1] / n - mean * mean;
    float inv  = rsqrtf(var + 1e-5f);
    float sc   = gamma[c] * inv;
    sb[2 * c]     = sc;
    sb[2 * c + 1] = beta[c] - mean * sc;
  }
}

// ---- main involution: per (b, g, 16x16 tile) ----
// out[b, g*4+cg, y, x] = sum_k kern[k] * h[b, g*4+cg, y+kh-3, x+kw-3]
// kern[k] = sum_c relu(bn(r[b,c,y,x])) * w_span[g*49+k, c]
__launch_bounds__(256)
__global__ void k_main(const float* __restrict__ h, const float* __restrict__ r,
                       const float* __restrict__ sb, const float* __restrict__ wspan,
                       float* __restrict__ out){
  __shared__ float s_h[4][22][23];                   // +1 pad col: worst 2-way bank alias (free)
  int t = threadIdx.x;
  int g = blockIdx.y, b = blockIdx.z;
  int tx0 = (blockIdx.x & 7) << 4, ty0 = (blockIdx.x >> 3) << 4;

  const float* hp = h + (((long)(b * 64 + g * 4)) << 14);
  for (int i = t; i < 1936; i += 256){               // 4 ch x 22 x 22 halo tile
    int cg = i / 484, rem = i - cg * 484;
    int ry = rem / 22, rx = rem - ry * 22;
    int yy = ty0 + ry - 3, xx = tx0 + rx - 3;
    float v = 0.f;
    if ((unsigned)yy < 128u && (unsigned)xx < 128u)
      v = hp[((long)cg << 14) + (yy << 7) + xx];
    s_h[cg][ry][rx] = v;
  }

  int ltx = t & 15, lty = t >> 4;
  int px = tx0 + ltx, py = ty0 + lty;
  const float* rp = r + ((long)b << 18) + (py << 7) + px;
  float rv[16];
  #pragma unroll
  for (int c = 0; c < 16; c++){
    float v = rp[(long)c << 14];
    rv[c] = fmaxf(v * sb[2 * c] + sb[2 * c + 1], 0.f);  // sb uniform -> s_load
  }
  __syncthreads();

  // kernel generation: w_span addresses are wave-uniform -> scalar-pipe s_loads
  const float* wsp = wspan + g * 784;
  float kern[49];
  #pragma unroll
  for (int k = 0; k < 49; k++){
    float a = 0.f;
    #pragma unroll
    for (int c = 0; c < 16; c++) a += rv[c] * wsp[k * 16 + c];
    kern[k] = a;
  }

  long obase = (((long)(b * 64 + g * 4)) << 14) + (py << 7) + px;
  #pragma unroll
  for (int cg = 0; cg < 4; cg++){
    float acc = 0.f;
    #pragma unroll
    for (int kh = 0; kh < 7; kh++)
      #pragma unroll
      for (int kw = 0; kw < 7; kw++)
        acc += kern[kh * 7 + kw] * s_h[cg][lty + kh][ltx + kw];
    out[obase + ((long)cg << 14)] = acc;
  }
}

extern "C" void kernel_launch(void* const* d_in, const int* in_sizes, int n_in,
                              void* d_out, int out_size, void* d_ws, size_t ws_size,
                              hipStream_t stream){
  const float* in       = (const float*)d_in[0];
  const float* w_dw     = (const float*)d_in[1];
  const float* w_pw     = (const float*)d_in[2];
  const float* gamma    = (const float*)d_in[3];
  const float* beta     = (const float*)d_in[4];
  const float* w_reduce = (const float*)d_in[5];
  const float* w_span   = (const float*)d_in[6];
  float* out = (float*)d_out;

  float* ws     = (float*)d_ws;
  float* tmp_dw = ws;                  // 4194304 floats
  float* h      = ws + 4194304;        // 4194304 floats
  float* r      = ws + 8388608;        // 1048576 floats
  float* stats  = ws + 9437184;        // 32 floats (sum, sumsq per channel)
  float* sb     = ws + 9437216;        // 32 floats (scale, bias per channel)

  k_zero<<<1, 64, 0, stream>>>(stats, 32);
  k_dw  <<<16384, 256, 0, stream>>>(in, w_dw, tmp_dw);
  k_pw  <<<1024, 256, 0, stream>>>(tmp_dw, w_pw, h);
  k_red <<<1024, 256, 0, stream>>>(in, w_reduce, r, stats);
  k_bn  <<<1, 16, 0, stream>>>(stats, gamma, beta, sb);
  dim3 grid(64, 16, 4);
  k_main<<<grid, 256, 0, stream>>>(h, r, sb, w_span, out);
}

// Round 5
// 165.479 us; speedup vs baseline: 1.7231x; 1.0973x over previous
//
#include <hip/hip_runtime.h>

// ---- zero small stats buffer (ws is poisoned 0xAA each call) ----
__global__ void k_zero(float* __restrict__ p, int n){
  int i = blockIdx.x * blockDim.x + threadIdx.x;
  if (i < n) p[i] = 0.f;
}

// ---- depthwise 3x3, pad 1: 4 x-consecutive px per thread, float4 store ----
__global__ void k_dw(const float* __restrict__ in, const float* __restrict__ w,
                     float* __restrict__ out){
  int idx = blockIdx.x * 256 + threadIdx.x;          // b*2^18 + c*2^12 + y*32 + xq
  int xq = (idx & 31) << 2;                          // x0 in {0,4,...,124}
  int y  = (idx >> 5) & 127;
  int c  = (idx >> 12) & 63;
  int b  = idx >> 18;
  const float* p = in + (((long)(b * 64 + c)) << 14);
  float wv[9];
  #pragma unroll
  for (int i = 0; i < 9; i++) wv[i] = w[c * 9 + i];
  float row[3][6];
  #pragma unroll
  for (int rr = 0; rr < 3; rr++){
    int yy = y + rr - 1;
    bool rok = (unsigned)yy < 128u;
    #pragma unroll
    for (int j = 0; j < 6; j++){
      int xx = xq + j - 1;
      row[rr][j] = (rok && (unsigned)xx < 128u) ? p[(yy << 7) + xx] : 0.f;
    }
  }
  float a[4];
  #pragma unroll
  for (int i = 0; i < 4; i++){
    float s = 0.f;
    #pragma unroll
    for (int rr = 0; rr < 3; rr++)
      #pragma unroll
      for (int d = 0; d < 3; d++) s += row[rr][i + d] * wv[rr * 3 + d];
    a[i] = s;
  }
  long base = (((long)(b * 64 + c)) << 14) + (y << 7) + xq;
  *(float4*)(out + base) = make_float4(a[0], a[1], a[2], a[3]);
}

// ---- pointwise 1x1: thread computes 16 of 64 outputs (q-chunk per block) ----
__launch_bounds__(256)
__global__ void k_pw(const float* __restrict__ dw, const float* __restrict__ wpw,
                     float* __restrict__ h){
  int blk = blockIdx.x;                              // b*256 + q*64 + sp_blk
  int sp = ((blk & 63) << 8) + threadIdx.x;
  int q  = (blk >> 6) & 3;                           // outputs 16q .. 16q+15
  int b  = blk >> 8;
  const float* p  = dw + ((long)b << 20) + sp;
  const float* wq = wpw + (q << 4) * 64;             // uniform per block -> s_load
  float acc[16];
  #pragma unroll
  for (int j = 0; j < 16; j++) acc[j] = 0.f;
  #pragma unroll 8
  for (int c = 0; c < 64; c++){
    float v = p[(long)c << 14];                      // coalesced across lanes
    #pragma unroll
    for (int j = 0; j < 16; j++) acc[j] += v * wq[j * 64 + c];
  }
  float* hp = h + ((long)b << 20) + ((long)q << 18) + sp;
  #pragma unroll
  for (int j = 0; j < 16; j++) hp[(long)j << 14] = acc[j];
}

// ---- reduce 1x1 (64->16): thread computes 4 of 16 outputs + BN stats ----
__launch_bounds__(256)
__global__ void k_red(const float* __restrict__ in, const float* __restrict__ wred,
                      float* __restrict__ r, float* __restrict__ stats){
  int blk = blockIdx.x;                              // b*256 + q*64 + sp_blk
  int sp = ((blk & 63) << 8) + threadIdx.x;
  int q  = (blk >> 6) & 3;                           // channels 4q .. 4q+3
  int b  = blk >> 8;
  const float* p  = in + ((long)b << 20) + sp;
  const float* wq = wred + (q << 2) * 64;            // uniform -> s_load
  float racc[4] = {0.f, 0.f, 0.f, 0.f};
  #pragma unroll 8
  for (int o = 0; o < 64; o++){
    float v = p[(long)o << 14];
    #pragma unroll
    for (int j = 0; j < 4; j++) racc[j] += v * wq[j * 64 + o];
  }
  float* rp = r + ((long)b << 18) + ((long)q << 16) + sp;
  #pragma unroll
  for (int j = 0; j < 4; j++) rp[(long)j << 14] = racc[j];

  // BN stats: wave shuffle-reduce (8 values), cross-wave via LDS, 8 atomics/block
  int lane = threadIdx.x & 63, wv = threadIdx.x >> 6;
  __shared__ float sw[4][8];
  #pragma unroll
  for (int j = 0; j < 4; j++){
    float v = racc[j], s2 = racc[j] * racc[j];
    #pragma unroll
    for (int off = 32; off > 0; off >>= 1){
      v  += __shfl_down(v,  off, 64);
      s2 += __shfl_down(s2, off, 64);
    }
    if (lane == 0){ sw[wv][2 * j] = v; sw[wv][2 * j + 1] = s2; }
  }
  __syncthreads();
  if (threadIdx.x < 8){
    float a = sw[0][threadIdx.x] + sw[1][threadIdx.x]
            + sw[2][threadIdx.x] + sw[3][threadIdx.x];
    atomicAdd(&stats[(q << 3) + threadIdx.x], a);    // stats[2c+s], c=4q+j
  }
}

// ---- BN finalize: scale/bias per channel (training-mode, biased var) ----
__global__ void k_bn(const float* __restrict__ stats, const float* __restrict__ gamma,
                     const float* __restrict__ beta, float* __restrict__ sb){
  int c = threadIdx.x;
  if (c < 16){
    const float n = 65536.f;                         // B*H*W
    float mean = stats[2 * c] / n;
    float var  = stats[2 * c + 1] / n - mean * mean;
    float inv  = rsqrtf(var + 1e-5f);
    float sc   = gamma[c] * inv;
    sb[2 * c]     = sc;
    sb[2 * c + 1] = beta[c] - mean * sc;
  }
}

// ---- main involution: per (b, g, 16x16 tile) ----
// LDS tile transposed to float4-per-point: one ds_read_b128 yields all 4 cg
// out[b, g*4+cg, y, x] = sum_k kern[k] * h[b, g*4+cg, y+kh-3, x+kw-3]
// kern[k] = sum_c relu(bn(r[b,c,y,x])) * w_span[g*49+k, c]
__launch_bounds__(256)
__global__ void k_main(const float* __restrict__ h, const float* __restrict__ r,
                       const float* __restrict__ sb, const float* __restrict__ wspan,
                       float* __restrict__ out){
  __shared__ float4 s_h4[22][24];                    // [row][col] -> 4 cg contiguous
  int t = threadIdx.x;
  int g = blockIdx.y, b = blockIdx.z;
  int tx0 = (blockIdx.x & 7) << 4, ty0 = (blockIdx.x >> 3) << 4;

  const float* hp = h + (((long)(b * 64 + g * 4)) << 14);
  for (int p = t; p < 484; p += 256){                // 22x22 halo points
    int ry = p / 22, rx = p - ry * 22;
    int yy = ty0 + ry - 3, xx = tx0 + rx - 3;
    float4 v = make_float4(0.f, 0.f, 0.f, 0.f);
    if ((unsigned)yy < 128u && (unsigned)xx < 128u){
      int o = (yy << 7) + xx;
      v.x = hp[o];
      v.y = hp[o + 16384];
      v.z = hp[o + 32768];
      v.w = hp[o + 49152];
    }
    s_h4[ry][rx] = v;
  }

  int ltx = t & 15, lty = t >> 4;
  int px = tx0 + ltx, py = ty0 + lty;
  const float* rp = r + ((long)b << 18) + (py << 7) + px;
  float rv[16];
  #pragma unroll
  for (int c = 0; c < 16; c++){
    float v = rp[(long)c << 14];
    rv[c] = fmaxf(v * sb[2 * c] + sb[2 * c + 1], 0.f);  // sb uniform -> s_load
  }
  __syncthreads();

  // fused kern-gen + conv: per tap, 16 FMA (kern) + 1 b128 + 4 FMA (conv)
  const float* wsp = wspan + g * 784;                // uniform -> scalar pipe
  float acc0 = 0.f, acc1 = 0.f, acc2 = 0.f, acc3 = 0.f;
  #pragma unroll
  for (int kh = 0; kh < 7; kh++){
    #pragma unroll
    for (int kw = 0; kw < 7; kw++){
      int k = kh * 7 + kw;
      float kv = 0.f;
      #pragma unroll
      for (int c = 0; c < 16; c++) kv += rv[c] * wsp[k * 16 + c];
      float4 hv = s_h4[lty + kh][ltx + kw];
      acc0 += kv * hv.x;
      acc1 += kv * hv.y;
      acc2 += kv * hv.z;
      acc3 += kv * hv.w;
    }
  }

  long obase = (((long)(b * 64 + g * 4)) << 14) + (py << 7) + px;
  out[obase]         = acc0;
  out[obase + 16384] = acc1;
  out[obase + 32768] = acc2;
  out[obase + 49152] = acc3;
}

extern "C" void kernel_launch(void* const* d_in, const int* in_sizes, int n_in,
                              void* d_out, int out_size, void* d_ws, size_t ws_size,
                              hipStream_t stream){
  const float* in       = (const float*)d_in[0];
  const float* w_dw     = (const float*)d_in[1];
  const float* w_pw     = (const float*)d_in[2];
  const float* gamma    = (const float*)d_in[3];
  const float* beta     = (const float*)d_in[4];
  const float* w_reduce = (const float*)d_in[5];
  const float* w_span   = (const float*)d_in[6];
  float* out = (float*)d_out;

  float* ws     = (float*)d_ws;
  float* tmp_dw = ws;                  // 4194304 floats
  float* h      = ws + 4194304;        // 4194304 floats
  float* r      = ws + 8388608;        // 1048576 floats
  float* stats  = ws + 9437184;        // 32 floats (sum, sumsq per channel)
  float* sb     = ws + 9437216;        // 32 floats (scale, bias per channel)

  k_zero<<<1, 64, 0, stream>>>(stats, 32);
  k_dw  <<<4096, 256, 0, stream>>>(in, w_dw, tmp_dw);
  k_pw  <<<1024, 256, 0, stream>>>(tmp_dw, w_pw, h);
  k_red <<<1024, 256, 0, stream>>>(in, w_reduce, r, stats);
  k_bn  <<<1, 16, 0, stream>>>(stats, gamma, beta, sb);
  dim3 grid(64, 16, 4);
  k_main<<<grid, 256, 0, stream>>>(h, r, sb, w_span, out);
}